// Round 1
// 230.878 us; speedup vs baseline: 1.0163x; 1.0163x over previous
//
#include <hip/hip_runtime.h>
#include <hip/hip_bf16.h>
#include <math.h>

// ---- problem constants ----
#define BROWS 16384
#define NF    10
#define EMB   32
#define DENSE 16
#define K0S   352   // 336 padded to 11 K-steps of 32
#define K0    336
#define N0    256
#define N1    128
#define N2    64
#define BN_INV 0.99999500003749969f  // 1/sqrt(1+1e-5)

__constant__ int c_offsets[NF] = {
    0, 1000000, 1100000, 1101008, 1102012,
    1102114, 1103114, 1103614, 1103664, 1103776
};

typedef short  bf16x8 __attribute__((ext_vector_type(8)));
typedef float  f32x4  __attribute__((ext_vector_type(4)));

static __device__ __forceinline__ unsigned short f2bf(float x) {
    union { float f; unsigned u; } c; c.f = x;
    unsigned r = (c.u + 0x7FFFu + ((c.u >> 16) & 1u)) >> 16;  // RNE
    return (unsigned short)r;
}
// hw v_cvt_pk_bf16_f32 on gfx950 (RNE)
static __device__ __forceinline__ unsigned pk2(float x, float y) {
    __hip_bfloat162 h = __float22bfloat162_rn(make_float2(x, y));
    union { __hip_bfloat162 h; unsigned u; } c; c.h = h; return c.u;
}
static __device__ __forceinline__ float bf2f(unsigned short h) {
    union { unsigned u; float f; } c; c.u = (unsigned)h << 16; return c.f;
}

// ---------------------------------------------------------------------------
// Weight fp32 -> bf16 conversion (W0 K-padded 336->352). 131072 elements.
// ---------------------------------------------------------------------------
__global__ __launch_bounds__(256) void k_wconv_all(
    const float* __restrict__ W0, const float* __restrict__ W1,
    const float* __restrict__ W2,
    unsigned short* __restrict__ W0b, unsigned short* __restrict__ W1b,
    unsigned short* __restrict__ W2b)
{
    int i = blockIdx.x * 256 + threadIdx.x;
    if (i < N0 * K0S) {
        int r = i / K0S, c = i - r * K0S;
        W0b[i] = f2bf(c < K0 ? W0[r * K0 + c] : 0.f);
    } else if (i < N0 * K0S + N1 * N0) {
        int j = i - N0 * K0S;
        W1b[j] = f2bf(W1[j]);
    } else {
        int j = i - (N0 * K0S + N1 * N0);
        W2b[j] = f2bf(W2[j]);
    }
}

// ---------------------------------------------------------------------------
// Fully fused kernel, restructured:
//   Phase A: cooperative index + bias gather + dense staging (coalesced)
//   Phase B: cooperative embedding gather -> bf16 A-tile in LDS
//            (2560 independent 16B loads, 10/thread, all in flight; each
//             128B emb row fetched exactly once per block)
//   Phase C: FM (first+second order) from staged tile, wave shfl reduce
//   Phase D/E/F: L0/L1/L2 MFMA; 4 waves = 4 N-quarters, each wave computes
//            BOTH 16-row groups so every W-frag load feeds 2 MFMAs
//   Phase G: BN2+ReLU+Wo-dot+sigmoid
// block = 256 thr (4 waves), 32 rows/block, grid = 512.
// MFMA 16x16x32 bf16: A[m=l16][k=quad*8+j]; B[n=l16][k=quad*8+j];
// C/D: col=l16, row=quad*4+reg.
// LDS strides (shorts): A 360, x1 264, h2 136 -> 16B-aligned rows, uniform
// bank spread for ds_read_b128 (8/bank = b128 minimum).
// ---------------------------------------------------------------------------
__global__ __launch_bounds__(256) void k_fused_all(
    const int*   __restrict__ sparse,    // [B, NF]
    const float* __restrict__ dense,     // [B, DENSE]
    const float* __restrict__ emb,       // [V, EMB]
    const float* __restrict__ bias_tab,  // [V]
    const float* __restrict__ fm_bias,   // [1]
    const unsigned short* __restrict__ W0b,  // [N0, K0S]
    const float* __restrict__ b0, const float* __restrict__ g0,
    const float* __restrict__ be0,
    const unsigned short* __restrict__ W1b,  // [N1, N0]
    const float* __restrict__ b1, const float* __restrict__ g1,
    const float* __restrict__ be1,
    const unsigned short* __restrict__ W2b,  // [N2, N1]
    const float* __restrict__ b2, const float* __restrict__ g2,
    const float* __restrict__ be2,
    const float* __restrict__ Wo,            // [N2]
    const float* __restrict__ bo,            // [1]
    float* __restrict__ out)                 // [B]
{
    __shared__ unsigned short As[32][360];   // bf16 A-tile, 23040 B
    __shared__ unsigned short x1s[32][264];  // 16896 B
    __shared__ unsigned short h2s[32][136];  // 8704 B
    __shared__ int   gidx[32][NF];
    __shared__ float biasp[32][NF];
    __shared__ float fmld[32];
    __shared__ float partial[4][32];

    const int tid = threadIdx.x;
    const int bm  = blockIdx.x * 32;

    // ---------------- phase A: indices + bias + dense + zero-pad ----------
#pragma unroll
    for (int i = 0; i < 2; ++i) {
        int p = tid + (i << 8);           // 0..511
        if (p < 320) {                    // 32 rows x 10 fields
            int row = p / NF, f = p - row * NF;
            int g = sparse[bm * NF + p] + c_offsets[f];   // coalesced
            gidx[row][f]  = g;
            biasp[row][f] = bias_tab[g];
        }
        {
            int row = p >> 4, d = p & 15;                 // 32 rows x 16
            As[row][320 + d] = f2bf(dense[bm * DENSE + p]); // coalesced
            As[row][336 + d] = 0;                         // K-pad zeros
        }
    }
    __syncthreads();

    // ---------------- phase B: embedding gather -> LDS bf16 tile ----------
    // 2560 chunks of 16B; chunk c: row=c/80, field=(c%80)/8, sub=c%8.
    // 8 consecutive threads fetch one 128B emb row contiguously.
#pragma unroll
    for (int i = 0; i < 10; ++i) {
        int c   = tid + (i << 8);
        int row = c / 80;
        int rem = c - row * 80;
        int f   = rem >> 3, sub = rem & 7;
        const float4 v = *(const float4*)(emb + (size_t)gidx[row][f] * EMB + (sub << 2));
        uint2 pk; pk.x = pk2(v.x, v.y); pk.y = pk2(v.z, v.w);
        *(uint2*)&As[row][(f << 5) + (sub << 2)] = pk;
    }
    __syncthreads();

    // ---------------- phase C: FM from staged tile ----------------
    // thread (rowA=tid>>5, e=tid&31) handles rows rowA, +8, +16, +24.
    {
        const int rowA = tid >> 5;   // 0..7
        const int e    = tid & 31;
        float s0 = 0.f, q0 = 0.f, s1 = 0.f, q1 = 0.f;
        float s2 = 0.f, q2 = 0.f, s3 = 0.f, q3 = 0.f;
#pragma unroll
        for (int f = 0; f < NF; ++f) {
            float a = bf2f(As[rowA     ][(f << 5) + e]);
            float b = bf2f(As[rowA +  8][(f << 5) + e]);
            float c = bf2f(As[rowA + 16][(f << 5) + e]);
            float d = bf2f(As[rowA + 24][(f << 5) + e]);
            s0 += a; q0 += a * a;
            s1 += b; q1 += b * b;
            s2 += c; q2 += c * c;
            s3 += d; q3 += d * d;
        }
        float r0 = 0.5f * (s0 * s0 - q0);
        float r1 = 0.5f * (s1 * s1 - q1);
        float r2 = 0.5f * (s2 * s2 - q2);
        float r3 = 0.5f * (s3 * s3 - q3);
        if (e < NF) {
            r0 += biasp[rowA     ][e];
            r1 += biasp[rowA +  8][e];
            r2 += biasp[rowA + 16][e];
            r3 += biasp[rowA + 24][e];
        }
#pragma unroll
        for (int m = 1; m < 32; m <<= 1) {
            r0 += __shfl_xor(r0, m); r1 += __shfl_xor(r1, m);
            r2 += __shfl_xor(r2, m); r3 += __shfl_xor(r3, m);
        }
        if (e == 0) {
            float fb = fm_bias[0];
            fmld[rowA     ] = fb + r0;
            fmld[rowA +  8] = fb + r1;
            fmld[rowA + 16] = fb + r2;
            fmld[rowA + 24] = fb + r3;
        }
    }

    const int lane = tid & 63;
    const int l16  = lane & 15;
    const int quad = lane >> 4;
    const int hh   = tid >> 6;     // wave = N-quarter (64 cols of L0)

    // ---------------- phase D: layer0 (352 -> 256) ----------------
    f32x4 acc1[2][4];
#pragma unroll
    for (int rg = 0; rg < 2; ++rg)
#pragma unroll
        for (int nt = 0; nt < 4; ++nt) acc1[rg][nt] = (f32x4){0.f, 0.f, 0.f, 0.f};

    const unsigned short* wp0 = W0b + (size_t)(hh * 64 + l16) * K0S + quad * 8;
#pragma unroll
    for (int ks = 0; ks < 11; ++ks) {
        bf16x8 a0 = *(const bf16x8*)&As[l16     ][(ks << 5) + (quad << 3)];
        bf16x8 a1 = *(const bf16x8*)&As[l16 + 16][(ks << 5) + (quad << 3)];
#pragma unroll
        for (int nt = 0; nt < 4; ++nt) {
            bf16x8 w = *(const bf16x8*)(wp0 + (size_t)(nt * 16) * K0S + ks * 32);
            acc1[0][nt] = __builtin_amdgcn_mfma_f32_16x16x32_bf16(a0, w, acc1[0][nt], 0, 0, 0);
            acc1[1][nt] = __builtin_amdgcn_mfma_f32_16x16x32_bf16(a1, w, acc1[1][nt], 0, 0, 0);
        }
    }
#pragma unroll
    for (int nt = 0; nt < 4; ++nt) {
        int col = hh * 64 + nt * 16 + l16;
        float sc = g0[col] * BN_INV;
        float tb = fmaf(b0[col], sc, be0[col]);
#pragma unroll
        for (int rg = 0; rg < 2; ++rg)
#pragma unroll
            for (int r = 0; r < 4; ++r) {
                float v = fmaf(acc1[rg][nt][r], sc, tb);
                v = v > 0.f ? v : 0.f;
                x1s[rg * 16 + quad * 4 + r][col] = f2bf(v);
            }
    }
    __syncthreads();

    // ---------------- phase E: layer1 (256 -> 128) ----------------
    f32x4 acc2[2][2];
#pragma unroll
    for (int rg = 0; rg < 2; ++rg)
#pragma unroll
        for (int nt = 0; nt < 2; ++nt) acc2[rg][nt] = (f32x4){0.f, 0.f, 0.f, 0.f};

    const unsigned short* wp1 = W1b + (size_t)(hh * 32 + l16) * N0 + quad * 8;
#pragma unroll
    for (int ks = 0; ks < 8; ++ks) {
        bf16x8 a0 = *(const bf16x8*)&x1s[l16     ][(ks << 5) + (quad << 3)];
        bf16x8 a1 = *(const bf16x8*)&x1s[l16 + 16][(ks << 5) + (quad << 3)];
#pragma unroll
        for (int nt = 0; nt < 2; ++nt) {
            bf16x8 w = *(const bf16x8*)(wp1 + (size_t)(nt * 16) * N0 + ks * 32);
            acc2[0][nt] = __builtin_amdgcn_mfma_f32_16x16x32_bf16(a0, w, acc2[0][nt], 0, 0, 0);
            acc2[1][nt] = __builtin_amdgcn_mfma_f32_16x16x32_bf16(a1, w, acc2[1][nt], 0, 0, 0);
        }
    }
#pragma unroll
    for (int nt = 0; nt < 2; ++nt) {
        int col = hh * 32 + nt * 16 + l16;
        float sc = g1[col] * BN_INV;
        float tb = fmaf(b1[col], sc, be1[col]);
#pragma unroll
        for (int rg = 0; rg < 2; ++rg)
#pragma unroll
            for (int r = 0; r < 4; ++r) {
                float v = fmaf(acc2[rg][nt][r], sc, tb);
                v = v > 0.f ? v : 0.f;
                h2s[rg * 16 + quad * 4 + r][col] = f2bf(v);
            }
    }
    __syncthreads();

    // ---------------- phase F: layer2 (128 -> 64) ----------------
    f32x4 acc3[2];
    acc3[0] = (f32x4){0.f, 0.f, 0.f, 0.f};
    acc3[1] = (f32x4){0.f, 0.f, 0.f, 0.f};
    const unsigned short* wp2 = W2b + (size_t)(hh * 16 + l16) * N1 + quad * 8;
#pragma unroll
    for (int ks = 0; ks < 4; ++ks) {
        bf16x8 a0 = *(const bf16x8*)&h2s[l16     ][(ks << 5) + (quad << 3)];
        bf16x8 a1 = *(const bf16x8*)&h2s[l16 + 16][(ks << 5) + (quad << 3)];
        bf16x8 w  = *(const bf16x8*)(wp2 + ks * 32);
        acc3[0] = __builtin_amdgcn_mfma_f32_16x16x32_bf16(a0, w, acc3[0], 0, 0, 0);
        acc3[1] = __builtin_amdgcn_mfma_f32_16x16x32_bf16(a1, w, acc3[1], 0, 0, 0);
    }

    // ---------------- phase G: BN2 + ReLU + Wo-dot + sigmoid ----------
    {
        int col = hh * 16 + l16;
        float sc = g2[col] * BN_INV;
        float tb = fmaf(b2[col], sc, be2[col]);
        float wo = Wo[col];
        float p0[4], p1[4];
#pragma unroll
        for (int r = 0; r < 4; ++r) {
            float v0 = fmaf(acc3[0][r], sc, tb); v0 = v0 > 0.f ? v0 : 0.f;
            float v1 = fmaf(acc3[1][r], sc, tb); v1 = v1 > 0.f ? v1 : 0.f;
            p0[r] = v0 * wo;
            p1[r] = v1 * wo;
        }
#pragma unroll
        for (int r = 0; r < 4; ++r) {
            p0[r] += __shfl_xor(p0[r], 1); p0[r] += __shfl_xor(p0[r], 2);
            p0[r] += __shfl_xor(p0[r], 4); p0[r] += __shfl_xor(p0[r], 8);
            p1[r] += __shfl_xor(p1[r], 1); p1[r] += __shfl_xor(p1[r], 2);
            p1[r] += __shfl_xor(p1[r], 4); p1[r] += __shfl_xor(p1[r], 8);
        }
        if (l16 == 0) {
#pragma unroll
            for (int r = 0; r < 4; ++r) {
                partial[hh][     quad * 4 + r] = p0[r];
                partial[hh][16 + quad * 4 + r] = p1[r];
            }
        }
    }
    __syncthreads();

    if (tid < 32) {
        float z = fmld[tid] + partial[0][tid] + partial[1][tid]
                + partial[2][tid] + partial[3][tid] + bo[0];
        out[bm + tid] = 1.f / (1.f + expf(-z));
    }
}

// ---------------------------------------------------------------------------
extern "C" void kernel_launch(void* const* d_in, const int* in_sizes, int n_in,
                              void* d_out, int out_size, void* d_ws, size_t ws_size,
                              hipStream_t stream)
{
    const int*   sparse   = (const int*)  d_in[0];
    const float* dense    = (const float*)d_in[1];
    const float* emb      = (const float*)d_in[2];
    const float* bias_tab = (const float*)d_in[3];
    const float* fm_bias  = (const float*)d_in[4];
    const float* Wo       = (const float*)d_in[5];
    const float* bo       = (const float*)d_in[6];
    const float* W0 = (const float*)d_in[7];
    const float* b0 = (const float*)d_in[8];
    const float* g0 = (const float*)d_in[9];
    const float* be0= (const float*)d_in[10];
    const float* W1 = (const float*)d_in[11];
    const float* b1 = (const float*)d_in[12];
    const float* g1 = (const float*)d_in[13];
    const float* be1= (const float*)d_in[14];
    const float* W2 = (const float*)d_in[15];
    const float* b2 = (const float*)d_in[16];
    const float* g2 = (const float*)d_in[17];
    const float* be2= (const float*)d_in[18];

    float* out = (float*)d_out;

    // workspace: converted weights only (256 KB)
    char* p = (char*)d_ws;
    unsigned short* W0b = (unsigned short*)p; p += (size_t)N0 * K0S * 2;
    unsigned short* W1b = (unsigned short*)p; p += (size_t)N1 * N0 * 2;
    unsigned short* W2b = (unsigned short*)p; p += (size_t)N2 * N1 * 2;

    k_wconv_all<<<(N0 * K0S + N1 * N0 + N2 * N1) / 256, 256, 0, stream>>>(
        W0, W1, W2, W0b, W1b, W2b);

    k_fused_all<<<BROWS / 32, 256, 0, stream>>>(
        sparse, dense, emb, bias_tab, fm_bias,
        W0b, b0, g0, be0, W1b, b1, g1, be1, W2b, b2, g2, be2,
        Wo, bo, out);
}